// Round 6
// baseline (682.814 us; speedup 1.0000x reference)
//
#include <hip/hip_runtime.h>

#define NF 128
#define EPS 1e-5f
#define NXCD 8

typedef unsigned short ushort_t;
typedef unsigned int uint_t;

// ---------------- graph prep (XCD-privatized histograms) ----------------

__global__ void k_hist8(const int* __restrict__ ei, int* __restrict__ sh,
                        int* __restrict__ dh, int E, int n) {
    int e = blockIdx.x * 256 + threadIdx.x;
    int c = blockIdx.x & (NXCD - 1);
    if (e < E) {
        atomicAdd(&sh[c * n + ei[e]], 1);
        atomicAdd(&dh[c * n + ei[E + e]], 1);
    }
}

// totals: dinv from src counts, dcnt from dst counts
__global__ void k_total(const int* __restrict__ sh, const int* __restrict__ dh,
                        float* __restrict__ dinv, int* __restrict__ dcnt, int n) {
    int i = blockIdx.x * 256 + threadIdx.x;
    if (i < n) {
        int s = 0, d = 0;
#pragma unroll
        for (int c = 0; c < NXCD; ++c) {
            s += sh[c * n + i];
            d += dh[c * n + i];
        }
        dinv[i] = rsqrtf((float)s + 1.0f);
        dcnt[i] = d;
    }
}

// padded row length: real edges + self, rounded up to 8 (MLP=8 in gather loop)
static __device__ inline int padlen(int c) { return (c + 8) & ~7; }

__global__ void scan1(const int* __restrict__ dcnt, int* __restrict__ part, int n) {
    int b = blockIdx.x, t = threadIdx.x;
    int base = b * 1024 + t * 4;
    int s = 0;
#pragma unroll
    for (int k = 0; k < 4; ++k) {
        int i = base + k;
        if (i < n) s += padlen(dcnt[i]);
    }
    __shared__ int red[256];
    red[t] = s;
    __syncthreads();
    for (int off = 128; off > 0; off >>= 1) {
        if (t < off) red[t] += red[t + off];
        __syncthreads();
    }
    if (t == 0) part[b] = red[0];
}

__global__ void scan2(int* __restrict__ part, int* __restrict__ rowptr, int nb, int n) {
    __shared__ int lds[256];
    int t = threadIdx.x;
    int v = (t < nb) ? part[t] : 0;
    lds[t] = v;
    __syncthreads();
    for (int off = 1; off < 256; off <<= 1) {
        int x = (t >= off) ? lds[t - off] : 0;
        __syncthreads();
        lds[t] += x;
        __syncthreads();
    }
    if (t < nb) part[t] = lds[t] - v;  // exclusive
    if (t == nb - 1) rowptr[n] = lds[t];
}

__global__ void scan3(const int* __restrict__ dcnt, const int* __restrict__ part,
                      int* __restrict__ rowptr, int n) {
    int b = blockIdx.x, t = threadIdx.x;
    int base = b * 1024 + t * 4;
    int c[4];
    int s = 0;
#pragma unroll
    for (int k = 0; k < 4; ++k) {
        int i = base + k;
        c[k] = (i < n) ? padlen(dcnt[i]) : 0;
        s += c[k];
    }
    __shared__ int lds[256];
    lds[t] = s;
    __syncthreads();
    for (int off = 1; off < 256; off <<= 1) {
        int x = (t >= off) ? lds[t - off] : 0;
        __syncthreads();
        lds[t] += x;
        __syncthreads();
    }
    int run = part[b] + lds[t] - s;
#pragma unroll
    for (int k = 0; k < 4; ++k) {
        int i = base + k;
        if (i < n) {
            rowptr[i] = run;
            run += c[k];
        }
    }
}

// per-copy cursors (exclusive scan of dh over copies), self edge, pad sentinels
__global__ void k_cursors(const int* __restrict__ rowptr, const int* __restrict__ dh,
                          const int* __restrict__ dcnt, int* __restrict__ cur,
                          int* __restrict__ colx, int n) {
    int i = blockIdx.x * 256 + threadIdx.x;
    if (i < n) {
        int base = rowptr[i];
#pragma unroll
        for (int c = 0; c < NXCD; ++c) {
            cur[c * n + i] = base;
            base += dh[c * n + i];
        }
        // base == rowptr[i] + dcnt[i]: self edge goes here
        colx[base] = i;
        int e1 = rowptr[i + 1];
        for (int q = base + 1; q < e1; ++q) colx[q] = n;  // zero-row sentinel
    }
}

__global__ void k_fill_csr8(const int* __restrict__ ei, int* cur,
                            int* __restrict__ colx, int E, int n) {
    int e = blockIdx.x * 256 + threadIdx.x;
    int c = blockIdx.x & (NXCD - 1);
    if (e < E) {
        int d = ei[E + e];
        int pos = atomicAdd(&cur[c * n + d], 1);
        colx[pos] = ei[e];
    }
}

// ---------------- batch norm ----------------

__global__ void bn_stats(const float* __restrict__ h, float* __restrict__ stats, int n) {
    int j = threadIdx.x & 127;
    int half = threadIdx.x >> 7;
    float s = 0.f, q = 0.f;
    for (int r = blockIdx.x * 2 + half; r < n; r += gridDim.x * 2) {
        float v = h[r * NF + j];
        s += v;
        q += v * v;
    }
    __shared__ float ls[256], lq[256];
    ls[threadIdx.x] = s; lq[threadIdx.x] = q;
    __syncthreads();
    if (threadIdx.x < 128) {
        atomicAdd(&stats[j], ls[threadIdx.x] + ls[threadIdx.x + 128]);
        atomicAdd(&stats[NF + j], lq[threadIdx.x] + lq[threadIdx.x + 128]);
    }
}

__global__ void bn_finalize(const float* __restrict__ stats, const float* __restrict__ g,
                            const float* __restrict__ b, float* __restrict__ ac,
                            float inv_n) {
    int j = threadIdx.x;  // 128 threads
    float mean = stats[j] * inv_n;
    float var = stats[NF + j] * inv_n - mean * mean;
    float rstd = rsqrtf(var + EPS);
    float a = g[j] * rstd;
    ac[j] = a;
    ac[NF + j] = b[j] - mean * a;
}

// ---------------- GEMM: out = opt_relu( (h*a + c) @ W + opt_bias ) ----------------

static __device__ inline ushort_t f2bf(float f) {
    uint_t u = __float_as_uint(f);
    return (ushort_t)((u + 0x7fffu + ((u >> 16) & 1u)) >> 16);
}

__launch_bounds__(256)
__global__ void gemm_bn(const float* __restrict__ Hh, const float* __restrict__ W,
                        const float* __restrict__ ac, const float* __restrict__ bias,
                        const float* __restrict__ rowscale,
                        float* __restrict__ out, ushort_t* __restrict__ outb,
                        int nrows, int relu, int obf) {
    __shared__ float hs[64][133];
    const int tid = threadIdx.x;
    const int tx = tid & 15;
    const int ty = tid >> 4;
    const int rb = blockIdx.x * 64;

#pragma unroll 8
    for (int p = 0; p < 32; ++p) {
        int idx = p * 256 + tid;
        int r = idx >> 7, k = idx & 127;
        int gr = rb + r;
        float v = (gr < nrows) ? Hh[(size_t)gr * NF + k] : 0.f;
        hs[r][k] = fmaf(v, ac[k], ac[NF + k]);
    }
    __syncthreads();

    float acc[4][8];
#pragma unroll
    for (int i = 0; i < 4; ++i)
#pragma unroll
        for (int j = 0; j < 8; ++j) acc[i][j] = 0.f;

    const int c0 = tx * 4, c1 = 64 + tx * 4;
#pragma unroll 4
    for (int k = 0; k < 128; ++k) {
        const float4 b0 = *(const float4*)&W[k * NF + c0];
        const float4 b1 = *(const float4*)&W[k * NF + c1];
#pragma unroll
        for (int i = 0; i < 4; ++i) {
            float a = hs[ty * 4 + i][k];
            acc[i][0] = fmaf(a, b0.x, acc[i][0]);
            acc[i][1] = fmaf(a, b0.y, acc[i][1]);
            acc[i][2] = fmaf(a, b0.z, acc[i][2]);
            acc[i][3] = fmaf(a, b0.w, acc[i][3]);
            acc[i][4] = fmaf(a, b1.x, acc[i][4]);
            acc[i][5] = fmaf(a, b1.y, acc[i][5]);
            acc[i][6] = fmaf(a, b1.z, acc[i][6]);
            acc[i][7] = fmaf(a, b1.w, acc[i][7]);
        }
    }

#pragma unroll
    for (int i = 0; i < 4; ++i) {
        int gr = rb + ty * 4 + i;
        if (gr < nrows) {
            float o[8];
#pragma unroll
            for (int j = 0; j < 8; ++j) {
                int c = (j < 4) ? (c0 + j) : (c1 + j - 4);
                float v = acc[i][j] + (bias ? bias[c] : 0.f);
                o[j] = relu ? fmaxf(v, 0.f) : v;
            }
            if (obf) {
                float rs = rowscale ? rowscale[gr] : 1.0f;
                ushort4 p0, p1;
                p0.x = f2bf(o[0] * rs); p0.y = f2bf(o[1] * rs);
                p0.z = f2bf(o[2] * rs); p0.w = f2bf(o[3] * rs);
                p1.x = f2bf(o[4] * rs); p1.y = f2bf(o[5] * rs);
                p1.z = f2bf(o[6] * rs); p1.w = f2bf(o[7] * rs);
                *(ushort4*)&outb[(size_t)gr * NF + c0] = p0;
                *(ushort4*)&outb[(size_t)gr * NF + c1] = p1;
            } else {
                *(float4*)&out[(size_t)gr * NF + c0] = make_float4(o[0], o[1], o[2], o[3]);
                *(float4*)&out[(size_t)gr * NF + c1] = make_float4(o[4], o[5], o[6], o[7]);
            }
        }
    }
}

// ---------------- GCN aggregation (lean: no LDS, no barrier, MLP=8) ----------------

#define CVT2(u, a, b) { a = __uint_as_float((u) << 16); b = __uint_as_float((u) & 0xffff0000u); }
#define ACC8(q) { float p0, p1, p2, p3, p4, p5, p6, p7;                          \
    CVT2(q.x, p0, p1) CVT2(q.y, p2, p3) CVT2(q.z, p4, p5) CVT2(q.w, p6, p7)      \
    acc[0] += p0; acc[1] += p1; acc[2] += p2; acc[3] += p3;                      \
    acc[4] += p4; acc[5] += p5; acc[6] += p6; acc[7] += p7; }

__launch_bounds__(256)
__global__ void k_aggregate_bf(const ushort_t* __restrict__ xwb, const int* __restrict__ rowptr,
                               const int* __restrict__ colx, const float* __restrict__ dinv,
                               const float* __restrict__ bias, float* __restrict__ out, int n) {
    int node = blockIdx.x * 16 + (threadIdx.x >> 4);
    int lane = threadIdx.x & 15;
    if (node >= n) return;
    const uint4* __restrict__ xq = (const uint4*)xwb;
    float acc[8];
#pragma unroll
    for (int j = 0; j < 8; ++j) acc[j] = 0.f;
    int e0 = rowptr[node], e1 = rowptr[node + 1];
    for (int e = e0; e < e1; e += 8) {
        int4 ca = *(const int4*)&colx[e];
        int4 cb = *(const int4*)&colx[e + 4];
        uint4 q0 = xq[(size_t)ca.x * 16 + lane];
        uint4 q1 = xq[(size_t)ca.y * 16 + lane];
        uint4 q2 = xq[(size_t)ca.z * 16 + lane];
        uint4 q3 = xq[(size_t)ca.w * 16 + lane];
        uint4 q4 = xq[(size_t)cb.x * 16 + lane];
        uint4 q5 = xq[(size_t)cb.y * 16 + lane];
        uint4 q6 = xq[(size_t)cb.z * 16 + lane];
        uint4 q7 = xq[(size_t)cb.w * 16 + lane];
        ACC8(q0) ACC8(q1) ACC8(q2) ACC8(q3)
        ACC8(q4) ACC8(q5) ACC8(q6) ACC8(q7)
    }
    float di = dinv[node];
    float4 b0 = *(const float4*)&bias[lane * 8];
    float4 b1 = *(const float4*)&bias[lane * 8 + 4];
    float4 o0, o1;
    o0.x = fmaxf(fmaf(di, acc[0], b0.x), 0.f);
    o0.y = fmaxf(fmaf(di, acc[1], b0.y), 0.f);
    o0.z = fmaxf(fmaf(di, acc[2], b0.z), 0.f);
    o0.w = fmaxf(fmaf(di, acc[3], b0.w), 0.f);
    o1.x = fmaxf(fmaf(di, acc[4], b1.x), 0.f);
    o1.y = fmaxf(fmaf(di, acc[5], b1.y), 0.f);
    o1.z = fmaxf(fmaf(di, acc[6], b1.z), 0.f);
    o1.w = fmaxf(fmaf(di, acc[7], b1.w), 0.f);
    *(float4*)&out[(size_t)node * NF + lane * 8] = o0;
    *(float4*)&out[(size_t)node * NF + lane * 8 + 4] = o1;
}

// ---------------- pooling (sorted batch, stats fused) ----------------

__global__ void k_pool(const float* __restrict__ h, const int* __restrict__ batch,
                       float* __restrict__ pooled, float* __restrict__ stats, int n) {
    int g = blockIdx.x;
    int t = threadIdx.x;  // 128
    int lo = 0, hi = n;
    while (lo < hi) { int m = (lo + hi) >> 1; if (batch[m] < g) lo = m + 1; else hi = m; }
    int start = lo;
    lo = start; hi = n;
    while (lo < hi) { int m = (lo + hi) >> 1; if (batch[m] < g + 1) lo = m + 1; else hi = m; }
    int end = lo;
    float a0 = 0.f, a1 = 0.f, a2 = 0.f, a3 = 0.f;
    int r = start;
    for (; r + 4 <= end; r += 4) {
        a0 += h[(size_t)r * NF + t];
        a1 += h[(size_t)(r + 1) * NF + t];
        a2 += h[(size_t)(r + 2) * NF + t];
        a3 += h[(size_t)(r + 3) * NF + t];
    }
    for (; r < end; ++r) a0 += h[(size_t)r * NF + t];
    float val = (a0 + a1) + (a2 + a3);
    pooled[g * NF + t] = val;
    atomicAdd(&stats[t], val);
    atomicAdd(&stats[NF + t], val * val);
}

// ---------------- classifier + log_softmax ----------------

__global__ void k_cls(const float* __restrict__ h, const float* __restrict__ ac,
                      const float* __restrict__ Wc, const float* __restrict__ bc,
                      float* __restrict__ out, int C_) {
    __shared__ float hr[128];
    __shared__ float lg[16];
    __shared__ float lse_s;
    int r = blockIdx.x, t = threadIdx.x;  // 64 threads
    hr[t]      = fmaf(h[r * NF + t],      ac[t],      ac[NF + t]);
    hr[t + 64] = fmaf(h[r * NF + 64 + t], ac[64 + t], ac[NF + 64 + t]);
    __syncthreads();
    if (t < C_) {
        float s = bc[t];
        for (int k = 0; k < 128; ++k) s = fmaf(hr[k], Wc[k * C_ + t], s);
        lg[t] = s;
    }
    __syncthreads();
    if (t == 0) {
        float m = -1e30f;
        for (int c = 0; c < C_; ++c) m = fmaxf(m, lg[c]);
        float se = 0.f;
        for (int c = 0; c < C_; ++c) se += expf(lg[c] - m);
        lse_s = m + logf(se);
    }
    __syncthreads();
    if (t < C_) out[r * C_ + t] = lg[t] - lse_s;
}

// ---------------- launch ----------------

extern "C" void kernel_launch(void* const* d_in, const int* in_sizes, int n_in,
                              void* d_out, int out_size, void* d_ws, size_t ws_size,
                              hipStream_t stream) {
    const float* x          = (const float*)d_in[0];
    const int*   ei         = (const int*)d_in[1];
    const int*   batch      = (const int*)d_in[2];
    const float* bn_feat_g  = (const float*)d_in[3];
    const float* bn_feat_b  = (const float*)d_in[4];
    const float* W_feat     = (const float*)d_in[5];
    const float* bns_conv_g = (const float*)d_in[6];
    const float* bns_conv_b = (const float*)d_in[7];
    const float* W_conv     = (const float*)d_in[8];
    const float* b_conv     = (const float*)d_in[9];
    const float* bn_fc_g    = (const float*)d_in[10];
    const float* bn_fc_b    = (const float*)d_in[11];
    const float* W_lin      = (const float*)d_in[12];
    const float* b_lin      = (const float*)d_in[13];
    const float* bn_hid_g   = (const float*)d_in[14];
    const float* bn_hid_b   = (const float*)d_in[15];
    const float* W_cls      = (const float*)d_in[16];
    const float* b_cls      = (const float*)d_in[17];
    float* outp = (float*)d_out;

    const int N_ = in_sizes[2];
    const int E_ = in_sizes[1] / 2;
    const int C_ = 10;
    const int G_ = out_size / C_;
    const int Epad = E_ + 8 * N_;        // padded CSR capacity (self + pad-to-8)
    const int NB1 = (N_ + 1023) / 1024;  // scan blocks (<=256)

    char* wsp = (char*)d_ws;
    auto alloc = [&](size_t bytes) {
        void* p = (void*)wsp;
        wsp += (bytes + 255) & ~(size_t)255;
        return p;
    };
    float*    A      = (float*)alloc((size_t)N_ * NF * 4);
    ushort_t* Bb     = (ushort_t*)alloc((size_t)(N_ + 1) * NF * 2);  // +1 zero row
    float*    dinv   = (float*)alloc((size_t)N_ * 4);
    int*      sh     = (int*)alloc((size_t)NXCD * N_ * 4);  // per-XCD src hist
    int*      dh     = (int*)alloc((size_t)NXCD * N_ * 4);  // per-XCD dst hist
    int*      cur    = (int*)alloc((size_t)NXCD * N_ * 4);  // per-XCD cursors
    int*      dcnt   = (int*)alloc((size_t)N_ * 4);
    int*      rowptr = (int*)alloc((size_t)(N_ + 1) * 4);
    int*      part   = (int*)alloc(256 * 4);
    int*      colx   = (int*)alloc((size_t)Epad * 4);
    float*    statsA = (float*)alloc(6 * 256 * 4);
    float*    ac     = (float*)alloc(256 * 4);
    float*    pooled = (float*)alloc((size_t)G_ * NF * 4);
    float*    y2     = (float*)alloc((size_t)G_ * NF * 4);

    float* st_x  = statsA;
    float* st_f  = statsA + 256;
    float* st_a1 = statsA + 512;
    float* st_a2 = statsA + 768;
    float* st_pl = statsA + 1024;
    float* st_y2 = statsA + 1280;

    int nb_n = (N_ + 255) / 256;
    int nb_e = (E_ + 255) / 256;

    hipMemsetAsync(sh, 0, (size_t)2 * NXCD * N_ * 4, stream);  // sh + dh contiguous
    hipMemsetAsync(statsA, 0, 6 * 256 * 4, stream);
    hipMemsetAsync(Bb + (size_t)N_ * NF, 0, NF * 2, stream);   // sentinel row

    // graph prep (XCD-local atomics throughout)
    k_hist8<<<nb_e, 256, 0, stream>>>(ei, sh, dh, E_, N_);
    k_total<<<nb_n, 256, 0, stream>>>(sh, dh, dinv, dcnt, N_);
    scan1<<<NB1, 256, 0, stream>>>(dcnt, part, N_);
    scan2<<<1, 256, 0, stream>>>(part, rowptr, NB1, N_);
    scan3<<<NB1, 256, 0, stream>>>(dcnt, part, rowptr, N_);
    k_cursors<<<nb_n, 256, 0, stream>>>(rowptr, dh, dcnt, cur, colx, N_);
    k_fill_csr8<<<nb_e, 256, 0, stream>>>(ei, cur, colx, E_, N_);

    // feat: A = relu( bn(x) @ W_feat )
    bn_stats<<<512, 256, 0, stream>>>(x, st_x, N_);
    bn_finalize<<<1, 128, 0, stream>>>(st_x, bn_feat_g, bn_feat_b, ac, 1.0f / N_);
    gemm_bn<<<(N_ + 63) / 64, 256, 0, stream>>>(x, W_feat, ac, nullptr, nullptr,
                                                A, nullptr, N_, 1, 0);
    bn_stats<<<512, 256, 0, stream>>>(A, st_f, N_);

    // conv layers
    float* st_in[3] = {st_f, st_a1, st_a2};
    float* st_out[3] = {st_a1, st_a2, nullptr};
    for (int l = 0; l < 3; ++l) {
        bn_finalize<<<1, 128, 0, stream>>>(st_in[l], bns_conv_g + l * NF,
                                           bns_conv_b + l * NF, ac, 1.0f / N_);
        gemm_bn<<<(N_ + 63) / 64, 256, 0, stream>>>(A, W_conv + (size_t)l * NF * NF, ac,
                                                    nullptr, dinv, nullptr, Bb, N_, 0, 1);
        k_aggregate_bf<<<(N_ + 15) / 16, 256, 0, stream>>>(Bb, rowptr, colx, dinv,
                                                           b_conv + l * NF, A, N_);
        if (st_out[l])
            bn_stats<<<512, 256, 0, stream>>>(A, st_out[l], N_);
    }

    // pool (stats fused)
    k_pool<<<G_, 128, 0, stream>>>(A, batch, pooled, st_pl, N_);

    // fc
    bn_finalize<<<1, 128, 0, stream>>>(st_pl, bn_fc_b == nullptr ? bn_fc_g : bn_fc_g, bn_fc_b, ac, 1.0f / G_);
    gemm_bn<<<(G_ + 63) / 64, 256, 0, stream>>>(pooled, W_lin, ac, b_lin, nullptr,
                                                y2, nullptr, G_, 1, 0);
    bn_stats<<<512, 256, 0, stream>>>(y2, st_y2, G_);

    // classifier
    bn_finalize<<<1, 128, 0, stream>>>(st_y2, bn_hid_g, bn_hid_b, ac, 1.0f / G_);
    k_cls<<<G_, 64, 0, stream>>>(y2, ac, W_cls, b_cls, outp, C_);
}

// Round 7
// 532.796 us; speedup vs baseline: 1.2816x; 1.2816x over previous
//
#include <hip/hip_runtime.h>

#define NF 128
#define EPS 1e-5f
#define KELL 64

typedef unsigned short ushort_t;
typedef unsigned int uint_t;

using bf16x8 = __attribute__((ext_vector_type(8))) short;
using f32x4  = __attribute__((ext_vector_type(4))) float;

static __device__ inline ushort_t f2bf(float f) {
    uint_t u = __float_as_uint(f);
    return (ushort_t)((u + 0x7fffu + ((u >> 16) & 1u)) >> 16);
}

// ---------------- graph prep: one-pass ELL build ----------------
// colx[d*64 + pos] = s ; scnt/dcnt histograms in same pass.

__global__ void k_fill_ell(const int* __restrict__ ei, int* __restrict__ scnt,
                           int* __restrict__ dcnt, int* __restrict__ colx, int E) {
    int e = blockIdx.x * 256 + threadIdx.x;
    if (e < E) {
        int s = ei[e], d = ei[E + e];
        atomicAdd(&scnt[s], 1);
        int pos = atomicAdd(&dcnt[d], 1);
        if (pos < KELL - 1) colx[d * KELL + pos] = s;  // slot 63 reserved for self
    }
}

// dinv, self edge, pad sentinels (row padded to multiple of 8 incl. self)
__global__ void k_finish(const int* __restrict__ scnt, const int* __restrict__ dcnt,
                         float* __restrict__ dinv, int* __restrict__ colx, int n) {
    int i = blockIdx.x * 256 + threadIdx.x;
    if (i < n) {
        dinv[i] = rsqrtf((float)scnt[i] + 1.0f);
        int dc = min(dcnt[i], KELL - 1);
        int base = i * KELL;
        colx[base + dc] = i;  // self loop
        int pl = (dc + 8) & ~7;
        for (int q = dc + 1; q < pl; ++q) colx[base + q] = n;  // zero-row sentinel
    }
}

// ---------------- batch norm ----------------

__global__ void bn_stats(const float* __restrict__ h, float* __restrict__ stats, int n) {
    int j = threadIdx.x & 127;
    int half = threadIdx.x >> 7;
    float s = 0.f, q = 0.f;
    for (int r = blockIdx.x * 2 + half; r < n; r += gridDim.x * 2) {
        float v = h[r * NF + j];
        s += v;
        q += v * v;
    }
    __shared__ float ls[256], lq[256];
    ls[threadIdx.x] = s; lq[threadIdx.x] = q;
    __syncthreads();
    if (threadIdx.x < 128) {
        atomicAdd(&stats[j], ls[threadIdx.x] + ls[threadIdx.x + 128]);
        atomicAdd(&stats[NF + j], lq[threadIdx.x] + lq[threadIdx.x + 128]);
    }
}

__global__ void bn_finalize(const float* __restrict__ stats, const float* __restrict__ g,
                            const float* __restrict__ b, float* __restrict__ ac,
                            float inv_n) {
    int j = threadIdx.x;  // 128 threads
    float mean = stats[j] * inv_n;
    float var = stats[NF + j] * inv_n - mean * mean;
    float rstd = rsqrtf(var + EPS);
    float a = g[j] * rstd;
    ac[j] = a;
    ac[NF + j] = b[j] - mean * a;
}

// ---------------- W pack: fp32 [128][128] -> bf16 B-fragment order ----------------
// Wp[((kc*8+ct)*64+lane)*8+j] = bf16(W[(kc*32+(lane>>4)*8+j)*128 + ct*16 + (lane&15)])

__global__ void pack_w(const float* __restrict__ W, ushort_t* __restrict__ Wp) {
    int idx = blockIdx.x * 256 + threadIdx.x;  // 0..2047
    int lane = idx & 63, ct = (idx >> 6) & 7, kc = idx >> 9;
    int m = lane & 15, q = lane >> 4;
    ushort_t o[8];
#pragma unroll
    for (int j = 0; j < 8; ++j)
        o[j] = f2bf(W[(kc * 32 + q * 8 + j) * NF + ct * 16 + m]);
    *(uint4*)&Wp[idx * 8] = *(uint4*)o;
}

// ---------------- MFMA GEMM: out = opt_relu( (h*a + c) @ W + opt_bias ) ----------------
// 64 rows x 128 cols per block, 4 waves, 16x16x32 bf16 MFMA.
// obf: write bf16(rowscale[r] * o) to outb.

#define HSTRIDE 136  // ushorts per row: 272 B, 16B-aligned

__launch_bounds__(256)
__global__ void gemm_mfma(const float* __restrict__ Hh, const ushort_t* __restrict__ Wp,
                          const float* __restrict__ ac, const float* __restrict__ bias,
                          const float* __restrict__ rowscale,
                          float* __restrict__ out, ushort_t* __restrict__ outb,
                          int nrows, int relu, int obf) {
    __shared__ ushort_t hs[64 * HSTRIDE];
    const int tid = threadIdx.x;
    const int rb = blockIdx.x * 64;
    const float4* ac4 = (const float4*)ac;

    // stage: BN'd bf16 rows into LDS (coalesced float4 reads)
#pragma unroll
    for (int p = 0; p < 8; ++p) {
        int idx = p * 256 + tid;        // 0..2047 float4s
        int r = idx >> 5, k4 = idx & 31;
        int gr = rb + r;
        float4 v = (gr < nrows) ? *(const float4*)&Hh[(size_t)gr * NF + k4 * 4]
                                : make_float4(0.f, 0.f, 0.f, 0.f);
        float4 a4 = ac4[k4], c4 = ac4[32 + k4];
        ushort_t o[4];
        o[0] = f2bf(fmaf(v.x, a4.x, c4.x));
        o[1] = f2bf(fmaf(v.y, a4.y, c4.y));
        o[2] = f2bf(fmaf(v.z, a4.z, c4.z));
        o[3] = f2bf(fmaf(v.w, a4.w, c4.w));
        *(uint2*)&hs[r * HSTRIDE + k4 * 4] = *(uint2*)o;
    }
    __syncthreads();

    const int wave = tid >> 6, lane = tid & 63;
    const int m = lane & 15, q = lane >> 4;
    const ushort_t* arow = &hs[(wave * 16 + m) * HSTRIDE];

    f32x4 acc[8];
#pragma unroll
    for (int ct = 0; ct < 8; ++ct) acc[ct] = (f32x4){0.f, 0.f, 0.f, 0.f};

#pragma unroll
    for (int kc = 0; kc < 4; ++kc) {
        bf16x8 af = *(const bf16x8*)&arow[kc * 32 + q * 8];
        const ushort_t* wp = Wp + kc * 4096 + lane * 8;
#pragma unroll
        for (int ct = 0; ct < 8; ++ct) {
            bf16x8 bfr = *(const bf16x8*)&wp[ct * 512];
            acc[ct] = __builtin_amdgcn_mfma_f32_16x16x32_bf16(af, bfr, acc[ct], 0, 0, 0);
        }
    }

    // epilogue: D[row = rb + wave*16 + q*4 + r][col = ct*16 + m]
#pragma unroll
    for (int r = 0; r < 4; ++r) {
        int grow = rb + wave * 16 + q * 4 + r;
        if (grow < nrows) {
            float rs = (obf && rowscale) ? rowscale[grow] : 1.0f;
#pragma unroll
            for (int ct = 0; ct < 8; ++ct) {
                int col = ct * 16 + m;
                float v = acc[ct][r] + (bias ? bias[col] : 0.f);
                if (relu) v = fmaxf(v, 0.f);
                if (obf) outb[(size_t)grow * NF + col] = f2bf(v * rs);
                else     out[(size_t)grow * NF + col] = v;
            }
        }
    }
}

// ---------------- vector GEMM (small fc path) ----------------

__launch_bounds__(256)
__global__ void gemm_bn(const float* __restrict__ Hh, const float* __restrict__ W,
                        const float* __restrict__ ac, const float* __restrict__ bias,
                        float* __restrict__ out, int nrows, int relu) {
    __shared__ float hsb[64][133];
    const int tid = threadIdx.x;
    const int tx = tid & 15;
    const int ty = tid >> 4;
    const int rb = blockIdx.x * 64;

#pragma unroll 8
    for (int p = 0; p < 32; ++p) {
        int idx = p * 256 + tid;
        int r = idx >> 7, k = idx & 127;
        int gr = rb + r;
        float v = (gr < nrows) ? Hh[(size_t)gr * NF + k] : 0.f;
        hsb[r][k] = fmaf(v, ac[k], ac[NF + k]);
    }
    __syncthreads();

    float acc[4][8];
#pragma unroll
    for (int i = 0; i < 4; ++i)
#pragma unroll
        for (int j = 0; j < 8; ++j) acc[i][j] = 0.f;

    const int c0 = tx * 4, c1 = 64 + tx * 4;
#pragma unroll 4
    for (int k = 0; k < 128; ++k) {
        const float4 b0 = *(const float4*)&W[k * NF + c0];
        const float4 b1 = *(const float4*)&W[k * NF + c1];
#pragma unroll
        for (int i = 0; i < 4; ++i) {
            float a = hsb[ty * 4 + i][k];
            acc[i][0] = fmaf(a, b0.x, acc[i][0]);
            acc[i][1] = fmaf(a, b0.y, acc[i][1]);
            acc[i][2] = fmaf(a, b0.z, acc[i][2]);
            acc[i][3] = fmaf(a, b0.w, acc[i][3]);
            acc[i][4] = fmaf(a, b1.x, acc[i][4]);
            acc[i][5] = fmaf(a, b1.y, acc[i][5]);
            acc[i][6] = fmaf(a, b1.z, acc[i][6]);
            acc[i][7] = fmaf(a, b1.w, acc[i][7]);
        }
    }

#pragma unroll
    for (int i = 0; i < 4; ++i) {
        int gr = rb + ty * 4 + i;
        if (gr < nrows) {
            float o[8];
#pragma unroll
            for (int j = 0; j < 8; ++j) {
                int c = (j < 4) ? (c0 + j) : (c1 + j - 4);
                float v = acc[i][j] + (bias ? bias[c] : 0.f);
                o[j] = relu ? fmaxf(v, 0.f) : v;
            }
            *(float4*)&out[(size_t)gr * NF + c0] = make_float4(o[0], o[1], o[2], o[3]);
            *(float4*)&out[(size_t)gr * NF + c1] = make_float4(o[4], o[5], o[6], o[7]);
        }
    }
}

// ---------------- GCN aggregation (ELL, lean, MLP=8) ----------------

#define CVT2(u, a, b) { a = __uint_as_float((u) << 16); b = __uint_as_float((u) & 0xffff0000u); }
#define ACC8(q) { float p0, p1, p2, p3, p4, p5, p6, p7;                          \
    CVT2(q.x, p0, p1) CVT2(q.y, p2, p3) CVT2(q.z, p4, p5) CVT2(q.w, p6, p7)      \
    acc[0] += p0; acc[1] += p1; acc[2] += p2; acc[3] += p3;                      \
    acc[4] += p4; acc[5] += p5; acc[6] += p6; acc[7] += p7; }

__launch_bounds__(256)
__global__ void k_aggregate_bf(const ushort_t* __restrict__ xwb, const int* __restrict__ dcnt,
                               const int* __restrict__ colx, const float* __restrict__ dinv,
                               const float* __restrict__ bias, float* __restrict__ out, int n) {
    int node = blockIdx.x * 16 + (threadIdx.x >> 4);
    int lane = threadIdx.x & 15;
    if (node >= n) return;
    const uint4* __restrict__ xq = (const uint4*)xwb;
    float acc[8];
#pragma unroll
    for (int j = 0; j < 8; ++j) acc[j] = 0.f;
    int e0 = node * KELL;
    int e1 = e0 + ((min(dcnt[node], KELL - 1) + 8) & ~7);
    for (int e = e0; e < e1; e += 8) {
        int4 ca = *(const int4*)&colx[e];
        int4 cb = *(const int4*)&colx[e + 4];
        uint4 q0 = xq[(size_t)ca.x * 16 + lane];
        uint4 q1 = xq[(size_t)ca.y * 16 + lane];
        uint4 q2 = xq[(size_t)ca.z * 16 + lane];
        uint4 q3 = xq[(size_t)ca.w * 16 + lane];
        uint4 q4 = xq[(size_t)cb.x * 16 + lane];
        uint4 q5 = xq[(size_t)cb.y * 16 + lane];
        uint4 q6 = xq[(size_t)cb.z * 16 + lane];
        uint4 q7 = xq[(size_t)cb.w * 16 + lane];
        ACC8(q0) ACC8(q1) ACC8(q2) ACC8(q3)
        ACC8(q4) ACC8(q5) ACC8(q6) ACC8(q7)
    }
    float di = dinv[node];
    float4 b0 = *(const float4*)&bias[lane * 8];
    float4 b1 = *(const float4*)&bias[lane * 8 + 4];
    float4 o0, o1;
    o0.x = fmaxf(fmaf(di, acc[0], b0.x), 0.f);
    o0.y = fmaxf(fmaf(di, acc[1], b0.y), 0.f);
    o0.z = fmaxf(fmaf(di, acc[2], b0.z), 0.f);
    o0.w = fmaxf(fmaf(di, acc[3], b0.w), 0.f);
    o1.x = fmaxf(fmaf(di, acc[4], b1.x), 0.f);
    o1.y = fmaxf(fmaf(di, acc[5], b1.y), 0.f);
    o1.z = fmaxf(fmaf(di, acc[6], b1.z), 0.f);
    o1.w = fmaxf(fmaf(di, acc[7], b1.w), 0.f);
    *(float4*)&out[(size_t)node * NF + lane * 8] = o0;
    *(float4*)&out[(size_t)node * NF + lane * 8 + 4] = o1;
}

// ---------------- pooling (sorted batch, stats fused) ----------------

__global__ void k_pool(const float* __restrict__ h, const int* __restrict__ batch,
                       float* __restrict__ pooled, float* __restrict__ stats, int n) {
    int g = blockIdx.x;
    int t = threadIdx.x;  // 128
    int lo = 0, hi = n;
    while (lo < hi) { int m = (lo + hi) >> 1; if (batch[m] < g) lo = m + 1; else hi = m; }
    int start = lo;
    lo = start; hi = n;
    while (lo < hi) { int m = (lo + hi) >> 1; if (batch[m] < g + 1) lo = m + 1; else hi = m; }
    int end = lo;
    float a0 = 0.f, a1 = 0.f, a2 = 0.f, a3 = 0.f;
    int r = start;
    for (; r + 4 <= end; r += 4) {
        a0 += h[(size_t)r * NF + t];
        a1 += h[(size_t)(r + 1) * NF + t];
        a2 += h[(size_t)(r + 2) * NF + t];
        a3 += h[(size_t)(r + 3) * NF + t];
    }
    for (; r < end; ++r) a0 += h[(size_t)r * NF + t];
    float val = (a0 + a1) + (a2 + a3);
    pooled[g * NF + t] = val;
    atomicAdd(&stats[t], val);
    atomicAdd(&stats[NF + t], val * val);
}

// ---------------- classifier + log_softmax ----------------

__global__ void k_cls(const float* __restrict__ h, const float* __restrict__ ac,
                      const float* __restrict__ Wc, const float* __restrict__ bc,
                      float* __restrict__ out, int C_) {
    __shared__ float hr[128];
    __shared__ float lg[16];
    __shared__ float lse_s;
    int r = blockIdx.x, t = threadIdx.x;  // 64 threads
    hr[t]      = fmaf(h[r * NF + t],      ac[t],      ac[NF + t]);
    hr[t + 64] = fmaf(h[r * NF + 64 + t], ac[64 + t], ac[NF + 64 + t]);
    __syncthreads();
    if (t < C_) {
        float s = bc[t];
        for (int k = 0; k < 128; ++k) s = fmaf(hr[k], Wc[k * C_ + t], s);
        lg[t] = s;
    }
    __syncthreads();
    if (t == 0) {
        float m = -1e30f;
        for (int c = 0; c < C_; ++c) m = fmaxf(m, lg[c]);
        float se = 0.f;
        for (int c = 0; c < C_; ++c) se += expf(lg[c] - m);
        lse_s = m + logf(se);
    }
    __syncthreads();
    if (t < C_) out[r * C_ + t] = lg[t] - lse_s;
}

// ---------------- launch ----------------

extern "C" void kernel_launch(void* const* d_in, const int* in_sizes, int n_in,
                              void* d_out, int out_size, void* d_ws, size_t ws_size,
                              hipStream_t stream) {
    const float* x          = (const float*)d_in[0];
    const int*   ei         = (const int*)d_in[1];
    const int*   batch      = (const int*)d_in[2];
    const float* bn_feat_g  = (const float*)d_in[3];
    const float* bn_feat_b  = (const float*)d_in[4];
    const float* W_feat     = (const float*)d_in[5];
    const float* bns_conv_g = (const float*)d_in[6];
    const float* bns_conv_b = (const float*)d_in[7];
    const float* W_conv     = (const float*)d_in[8];
    const float* b_conv     = (const float*)d_in[9];
    const float* bn_fc_g    = (const float*)d_in[10];
    const float* bn_fc_b    = (const float*)d_in[11];
    const float* W_lin      = (const float*)d_in[12];
    const float* b_lin      = (const float*)d_in[13];
    const float* bn_hid_g   = (const float*)d_in[14];
    const float* bn_hid_b   = (const float*)d_in[15];
    const float* W_cls      = (const float*)d_in[16];
    const float* b_cls      = (const float*)d_in[17];
    float* outp = (float*)d_out;

    const int N_ = in_sizes[2];
    const int E_ = in_sizes[1] / 2;
    const int C_ = 10;
    const int G_ = out_size / C_;

    char* wsp = (char*)d_ws;
    auto alloc = [&](size_t bytes) {
        void* p = (void*)wsp;
        wsp += (bytes + 255) & ~(size_t)255;
        return p;
    };
    float*    A      = (float*)alloc((size_t)N_ * NF * 4);
    ushort_t* Bb     = (ushort_t*)alloc((size_t)(N_ + 1) * NF * 2);  // +1 zero row
    float*    dinv   = (float*)alloc((size_t)N_ * 4);
    int*      cnts   = (int*)alloc((size_t)2 * N_ * 4);     // scnt | dcnt
    int*      colx   = (int*)alloc((size_t)N_ * KELL * 4);  // ELL, stride 64
    ushort_t* Wp     = (ushort_t*)alloc((size_t)NF * NF * 2);
    float*    statsA = (float*)alloc(6 * 256 * 4);
    float*    ac     = (float*)alloc(256 * 4);
    float*    pooled = (float*)alloc((size_t)G_ * NF * 4);
    float*    y2     = (float*)alloc((size_t)G_ * NF * 4);

    int* scnt = cnts;
    int* dcnt = cnts + N_;
    float* st_x  = statsA;
    float* st_f  = statsA + 256;
    float* st_a1 = statsA + 512;
    float* st_a2 = statsA + 768;
    float* st_pl = statsA + 1024;
    float* st_y2 = statsA + 1280;

    int nb_n = (N_ + 255) / 256;
    int nb_e = (E_ + 255) / 256;
    int nb_g = (N_ + 63) / 64;

    hipMemsetAsync(cnts, 0, (size_t)2 * N_ * 4, stream);
    hipMemsetAsync(statsA, 0, 6 * 256 * 4, stream);
    hipMemsetAsync(Bb + (size_t)N_ * NF, 0, NF * 2, stream);  // sentinel row

    // graph prep: single atomic pass + finish
    k_fill_ell<<<nb_e, 256, 0, stream>>>(ei, scnt, dcnt, colx, E_);
    k_finish<<<nb_n, 256, 0, stream>>>(scnt, dcnt, dinv, colx, N_);

    // feat: A = relu( bn(x) @ W_feat )
    bn_stats<<<512, 256, 0, stream>>>(x, st_x, N_);
    bn_finalize<<<1, 128, 0, stream>>>(st_x, bn_feat_g, bn_feat_b, ac, 1.0f / N_);
    pack_w<<<8, 256, 0, stream>>>(W_feat, Wp);
    gemm_mfma<<<nb_g, 256, 0, stream>>>(x, Wp, ac, nullptr, nullptr,
                                        A, nullptr, N_, 1, 0);
    bn_stats<<<512, 256, 0, stream>>>(A, st_f, N_);

    // conv layers
    float* st_in[3] = {st_f, st_a1, st_a2};
    float* st_out[3] = {st_a1, st_a2, nullptr};
    for (int l = 0; l < 3; ++l) {
        bn_finalize<<<1, 128, 0, stream>>>(st_in[l], bns_conv_g + l * NF,
                                           bns_conv_b + l * NF, ac, 1.0f / N_);
        pack_w<<<8, 256, 0, stream>>>(W_conv + (size_t)l * NF * NF, Wp);
        gemm_mfma<<<nb_g, 256, 0, stream>>>(A, Wp, ac, nullptr, dinv,
                                            nullptr, Bb, N_, 0, 1);
        k_aggregate_bf<<<(N_ + 15) / 16, 256, 0, stream>>>(Bb, dcnt, colx, dinv,
                                                           b_conv + l * NF, A, N_);
        if (st_out[l])
            bn_stats<<<512, 256, 0, stream>>>(A, st_out[l], N_);
    }

    // pool (stats fused)
    k_pool<<<G_, 128, 0, stream>>>(A, batch, pooled, st_pl, N_);

    // fc (small: vector path)
    bn_finalize<<<1, 128, 0, stream>>>(st_pl, bn_fc_g, bn_fc_b, ac, 1.0f / G_);
    gemm_bn<<<(G_ + 63) / 64, 256, 0, stream>>>(pooled, W_lin, ac, b_lin, y2, G_, 1);
    bn_stats<<<512, 256, 0, stream>>>(y2, st_y2, G_);

    // classifier
    bn_finalize<<<1, 128, 0, stream>>>(st_y2, bn_hid_g, bn_hid_b, ac, 1.0f / G_);
    k_cls<<<G_, 64, 0, stream>>>(y2, ac, W_cls, b_cls, outp, C_);
}

// Round 8
// 511.630 us; speedup vs baseline: 1.3346x; 1.0414x over previous
//
#include <hip/hip_runtime.h>

#define NF 128
#define EPS 1e-5f
#define KELL 64

typedef unsigned short ushort_t;
typedef unsigned int uint_t;

using bf16x8 = __attribute__((ext_vector_type(8))) short;
using f32x4  = __attribute__((ext_vector_type(4))) float;

static __device__ inline ushort_t f2bf(float f) {
    uint_t u = __float_as_uint(f);
    return (ushort_t)((u + 0x7fffu + ((u >> 16) & 1u)) >> 16);
}

// ---------------- graph prep: one-pass ELL build (ushort cols) ----------------

__global__ void k_fill_ell(const int* __restrict__ ei, int* __restrict__ scnt,
                           int* __restrict__ dcnt, ushort_t* __restrict__ colx, int E) {
    int e = blockIdx.x * 256 + threadIdx.x;
    if (e < E) {
        int s = ei[e], d = ei[E + e];
        atomicAdd(&scnt[s], 1);
        int pos = atomicAdd(&dcnt[d], 1);
        if (pos < KELL - 1) colx[d * KELL + pos] = (ushort_t)s;  // slot 63 kept for self
    }
}

// dinv, self edge, pad sentinels to multiple of 16, zero Bb sentinel row
__global__ void k_finish(const int* __restrict__ scnt, const int* __restrict__ dcnt,
                         float* __restrict__ dinv, ushort_t* __restrict__ colx,
                         ushort_t* __restrict__ BbSent, int n) {
    int i = blockIdx.x * 256 + threadIdx.x;
    if (i < n) {
        dinv[i] = rsqrtf((float)scnt[i] + 1.0f);
        int dc = min(dcnt[i], KELL - 1);
        ushort_t* row = colx + i * KELL;
        row[dc] = (ushort_t)i;  // self loop
        int len = (dc + 16) & ~15;  // == ((dc+1)+15)&~15, <= 64
        for (int q = dc + 1; q < len; ++q) row[q] = (ushort_t)n;  // zero-row sentinel
    }
    if (blockIdx.x == 0 && threadIdx.x < 64)
        ((uint_t*)BbSent)[threadIdx.x] = 0;  // zero the sentinel bf16 row
}

// ---------------- batch norm stats ----------------

__global__ void bn_stats(const float* __restrict__ h, float* __restrict__ stats, int n) {
    int j = threadIdx.x & 127;
    int half = threadIdx.x >> 7;
    float s = 0.f, q = 0.f;
    for (int r = blockIdx.x * 2 + half; r < n; r += gridDim.x * 2) {
        float v = h[r * NF + j];
        s += v;
        q += v * v;
    }
    __shared__ float ls[256], lq[256];
    ls[threadIdx.x] = s; lq[threadIdx.x] = q;
    __syncthreads();
    if (threadIdx.x < 128) {
        atomicAdd(&stats[j], ls[threadIdx.x] + ls[threadIdx.x + 128]);
        atomicAdd(&stats[NF + j], lq[threadIdx.x] + lq[threadIdx.x + 128]);
    }
}

// ---------------- W pack: 4 matrices fp32 [128][128] -> bf16 B-fragment order ----------------

__global__ void pack_w4(const float* __restrict__ W0, const float* __restrict__ W123,
                        ushort_t* __restrict__ Wp) {
    int gidx = blockIdx.x * 256 + threadIdx.x;  // 0..8191
    int mat = gidx >> 11, idx = gidx & 2047;
    const float* W = (mat == 0) ? W0 : (W123 + (size_t)(mat - 1) * NF * NF);
    int lane = idx & 63, ct = (idx >> 6) & 7, kc = idx >> 9;
    int m = lane & 15, q = lane >> 4;
    ushort_t o[8];
#pragma unroll
    for (int j = 0; j < 8; ++j)
        o[j] = f2bf(W[(kc * 32 + q * 8 + j) * NF + ct * 16 + m]);
    *(uint4*)&Wp[(size_t)gidx * 8] = *(uint4*)o;
}

// ---------------- MFMA GEMM with fused BN-finalize prologue ----------------
// ac computed from raw stats in-block. obf: write bf16(rowscale[r]*o) to outb.

#define HSTRIDE 136  // ushorts per row: 272 B, 16B-aligned

__launch_bounds__(256)
__global__ void gemm_mfma(const float* __restrict__ Hh, const ushort_t* __restrict__ Wp,
                          const float* __restrict__ stats, const float* __restrict__ gW,
                          const float* __restrict__ bB, float inv_n,
                          const float* __restrict__ bias, const float* __restrict__ rowscale,
                          float* __restrict__ out, ushort_t* __restrict__ outb,
                          int nrows, int relu, int obf) {
    __shared__ ushort_t hs[64 * HSTRIDE];
    __shared__ float acs[256];
    const int tid = threadIdx.x;
    const int rb = blockIdx.x * 64;

    if (tid < 128) {
        float mean = stats[tid] * inv_n;
        float var = stats[NF + tid] * inv_n - mean * mean;
        float rstd = rsqrtf(var + EPS);
        float a = gW[tid] * rstd;
        acs[tid] = a;
        acs[NF + tid] = bB[tid] - mean * a;
    }
    __syncthreads();
    const float4* ac4 = (const float4*)acs;

    // stage: BN'd bf16 rows into LDS (coalesced float4 reads)
#pragma unroll
    for (int p = 0; p < 8; ++p) {
        int idx = p * 256 + tid;        // 0..2047 float4s
        int r = idx >> 5, k4 = idx & 31;
        int gr = rb + r;
        float4 v = (gr < nrows) ? *(const float4*)&Hh[(size_t)gr * NF + k4 * 4]
                                : make_float4(0.f, 0.f, 0.f, 0.f);
        float4 a4 = ac4[k4], c4 = ac4[32 + k4];
        ushort_t o[4];
        o[0] = f2bf(fmaf(v.x, a4.x, c4.x));
        o[1] = f2bf(fmaf(v.y, a4.y, c4.y));
        o[2] = f2bf(fmaf(v.z, a4.z, c4.z));
        o[3] = f2bf(fmaf(v.w, a4.w, c4.w));
        *(uint2*)&hs[r * HSTRIDE + k4 * 4] = *(uint2*)o;
    }
    __syncthreads();

    const int wave = tid >> 6, lane = tid & 63;
    const int m = lane & 15, q = lane >> 4;
    const ushort_t* arow = &hs[(wave * 16 + m) * HSTRIDE];

    f32x4 acc[8];
#pragma unroll
    for (int ct = 0; ct < 8; ++ct) acc[ct] = (f32x4){0.f, 0.f, 0.f, 0.f};

#pragma unroll
    for (int kc = 0; kc < 4; ++kc) {
        bf16x8 af = *(const bf16x8*)&arow[kc * 32 + q * 8];
        const ushort_t* wp = Wp + kc * 4096 + lane * 8;
#pragma unroll
        for (int ct = 0; ct < 8; ++ct) {
            bf16x8 bfr = *(const bf16x8*)&wp[ct * 512];
            acc[ct] = __builtin_amdgcn_mfma_f32_16x16x32_bf16(af, bfr, acc[ct], 0, 0, 0);
        }
    }

    // epilogue: D[row = rb + wave*16 + q*4 + r][col = ct*16 + m]
#pragma unroll
    for (int r = 0; r < 4; ++r) {
        int grow = rb + wave * 16 + q * 4 + r;
        if (grow < nrows) {
            float rs = (obf && rowscale) ? rowscale[grow] : 1.0f;
#pragma unroll
            for (int ct = 0; ct < 8; ++ct) {
                int col = ct * 16 + m;
                float v = acc[ct][r] + (bias ? bias[col] : 0.f);
                if (relu) v = fmaxf(v, 0.f);
                if (obf) outb[(size_t)grow * NF + col] = f2bf(v * rs);
                else     out[(size_t)grow * NF + col] = v;
            }
        }
    }
}

// ---------------- vector GEMM (small fc path), fused BN-finalize ----------------

__launch_bounds__(256)
__global__ void gemm_bn(const float* __restrict__ Hh, const float* __restrict__ W,
                        const float* __restrict__ stats, const float* __restrict__ gW,
                        const float* __restrict__ bB, float inv_n,
                        const float* __restrict__ bias,
                        float* __restrict__ out, int nrows, int relu) {
    __shared__ float hsb[64][133];
    __shared__ float acs[256];
    const int tid = threadIdx.x;
    const int tx = tid & 15;
    const int ty = tid >> 4;
    const int rb = blockIdx.x * 64;

    if (tid < 128) {
        float mean = stats[tid] * inv_n;
        float var = stats[NF + tid] * inv_n - mean * mean;
        float rstd = rsqrtf(var + EPS);
        float a = gW[tid] * rstd;
        acs[tid] = a;
        acs[NF + tid] = bB[tid] - mean * a;
    }
    __syncthreads();

#pragma unroll 8
    for (int p = 0; p < 32; ++p) {
        int idx = p * 256 + tid;
        int r = idx >> 7, k = idx & 127;
        int gr = rb + r;
        float v = (gr < nrows) ? Hh[(size_t)gr * NF + k] : 0.f;
        hsb[r][k] = fmaf(v, acs[k], acs[NF + k]);
    }
    __syncthreads();

    float acc[4][8];
#pragma unroll
    for (int i = 0; i < 4; ++i)
#pragma unroll
        for (int j = 0; j < 8; ++j) acc[i][j] = 0.f;

    const int c0 = tx * 4, c1 = 64 + tx * 4;
#pragma unroll 4
    for (int k = 0; k < 128; ++k) {
        const float4 b0 = *(const float4*)&W[k * NF + c0];
        const float4 b1 = *(const float4*)&W[k * NF + c1];
#pragma unroll
        for (int i = 0; i < 4; ++i) {
            float a = hsb[ty * 4 + i][k];
            acc[i][0] = fmaf(a, b0.x, acc[i][0]);
            acc[i][1] = fmaf(a, b0.y, acc[i][1]);
            acc[i][2] = fmaf(a, b0.z, acc[i][2]);
            acc[i][3] = fmaf(a, b0.w, acc[i][3]);
            acc[i][4] = fmaf(a, b1.x, acc[i][4]);
            acc[i][5] = fmaf(a, b1.y, acc[i][5]);
            acc[i][6] = fmaf(a, b1.z, acc[i][6]);
            acc[i][7] = fmaf(a, b1.w, acc[i][7]);
        }
    }

#pragma unroll
    for (int i = 0; i < 4; ++i) {
        int gr = rb + ty * 4 + i;
        if (gr < nrows) {
            float o[8];
#pragma unroll
            for (int j = 0; j < 8; ++j) {
                int c = (j < 4) ? (c0 + j) : (c1 + j - 4);
                float v = acc[i][j] + (bias ? bias[c] : 0.f);
                o[j] = relu ? fmaxf(v, 0.f) : v;
            }
            *(float4*)&out[(size_t)gr * NF + c0] = make_float4(o[0], o[1], o[2], o[3]);
            *(float4*)&out[(size_t)gr * NF + c1] = make_float4(o[4], o[5], o[6], o[7]);
        }
    }
}

// ---------------- GCN aggregation (ELL, ushort cols, MLP=16) ----------------

#define CVT2(u, a, b) { a = __uint_as_float((u) << 16); b = __uint_as_float((u) & 0xffff0000u); }
#define ACC8(q) { float p0, p1, p2, p3, p4, p5, p6, p7;                          \
    CVT2(q.x, p0, p1) CVT2(q.y, p2, p3) CVT2(q.z, p4, p5) CVT2(q.w, p6, p7)      \
    acc[0] += p0; acc[1] += p1; acc[2] += p2; acc[3] += p3;                      \
    acc[4] += p4; acc[5] += p5; acc[6] += p6; acc[7] += p7; }

__launch_bounds__(256)
__global__ void k_aggregate_bf(const ushort_t* __restrict__ xwb, const int* __restrict__ dcnt,
                               const ushort_t* __restrict__ colx, const float* __restrict__ dinv,
                               const float* __restrict__ bias, float* __restrict__ out, int n) {
    int node = blockIdx.x * 16 + (threadIdx.x >> 4);
    int lane = threadIdx.x & 15;
    if (node >= n) return;
    const uint4* __restrict__ xq = (const uint4*)xwb;
    float acc[8];
#pragma unroll
    for (int j = 0; j < 8; ++j) acc[j] = 0.f;
    int dc = min(dcnt[node], KELL - 1);
    int len = (dc + 16) & ~15;
    int e0 = node * KELL;
    for (int e = e0; e < e0 + len; e += 16) {
        uint4 ia = *(const uint4*)&colx[e];      // 8 packed ushort indices
        uint4 ib = *(const uint4*)&colx[e + 8];
        int i0 = ia.x & 0xffff, i1 = ia.x >> 16;
        int i2 = ia.y & 0xffff, i3 = ia.y >> 16;
        int i4 = ia.z & 0xffff, i5 = ia.z >> 16;
        int i6 = ia.w & 0xffff, i7 = ia.w >> 16;
        int i8 = ib.x & 0xffff, i9 = ib.x >> 16;
        int iA = ib.y & 0xffff, iB = ib.y >> 16;
        int iC = ib.z & 0xffff, iD = ib.z >> 16;
        int iE = ib.w & 0xffff, iF = ib.w >> 16;
        uint4 q0 = xq[(size_t)i0 * 16 + lane];
        uint4 q1 = xq[(size_t)i1 * 16 + lane];
        uint4 q2 = xq[(size_t)i2 * 16 + lane];
        uint4 q3 = xq[(size_t)i3 * 16 + lane];
        uint4 q4 = xq[(size_t)i4 * 16 + lane];
        uint4 q5 = xq[(size_t)i5 * 16 + lane];
        uint4 q6 = xq[(size_t)i6 * 16 + lane];
        uint4 q7 = xq[(size_t)i7 * 16 + lane];
        uint4 q8 = xq[(size_t)i8 * 16 + lane];
        uint4 q9 = xq[(size_t)i9 * 16 + lane];
        uint4 qA = xq[(size_t)iA * 16 + lane];
        uint4 qB = xq[(size_t)iB * 16 + lane];
        uint4 qC = xq[(size_t)iC * 16 + lane];
        uint4 qD = xq[(size_t)iD * 16 + lane];
        uint4 qE = xq[(size_t)iE * 16 + lane];
        uint4 qF = xq[(size_t)iF * 16 + lane];
        ACC8(q0) ACC8(q1) ACC8(q2) ACC8(q3)
        ACC8(q4) ACC8(q5) ACC8(q6) ACC8(q7)
        ACC8(q8) ACC8(q9) ACC8(qA) ACC8(qB)
        ACC8(qC) ACC8(qD) ACC8(qE) ACC8(qF)
    }
    float di = dinv[node];
    float4 b0 = *(const float4*)&bias[lane * 8];
    float4 b1 = *(const float4*)&bias[lane * 8 + 4];
    float4 o0, o1;
    o0.x = fmaxf(fmaf(di, acc[0], b0.x), 0.f);
    o0.y = fmaxf(fmaf(di, acc[1], b0.y), 0.f);
    o0.z = fmaxf(fmaf(di, acc[2], b0.z), 0.f);
    o0.w = fmaxf(fmaf(di, acc[3], b0.w), 0.f);
    o1.x = fmaxf(fmaf(di, acc[4], b1.x), 0.f);
    o1.y = fmaxf(fmaf(di, acc[5], b1.y), 0.f);
    o1.z = fmaxf(fmaf(di, acc[6], b1.z), 0.f);
    o1.w = fmaxf(fmaf(di, acc[7], b1.w), 0.f);
    *(float4*)&out[(size_t)node * NF + lane * 8] = o0;
    *(float4*)&out[(size_t)node * NF + lane * 8 + 4] = o1;
}

// ---------------- pooling (sorted batch, stats fused) ----------------

__global__ void k_pool(const float* __restrict__ h, const int* __restrict__ batch,
                       float* __restrict__ pooled, float* __restrict__ stats, int n) {
    int g = blockIdx.x;
    int t = threadIdx.x;  // 128
    int lo = 0, hi = n;
    while (lo < hi) { int m = (lo + hi) >> 1; if (batch[m] < g) lo = m + 1; else hi = m; }
    int start = lo;
    lo = start; hi = n;
    while (lo < hi) { int m = (lo + hi) >> 1; if (batch[m] < g + 1) lo = m + 1; else hi = m; }
    int end = lo;
    float a0 = 0.f, a1 = 0.f, a2 = 0.f, a3 = 0.f;
    int r = start;
    for (; r + 4 <= end; r += 4) {
        a0 += h[(size_t)r * NF + t];
        a1 += h[(size_t)(r + 1) * NF + t];
        a2 += h[(size_t)(r + 2) * NF + t];
        a3 += h[(size_t)(r + 3) * NF + t];
    }
    for (; r < end; ++r) a0 += h[(size_t)r * NF + t];
    float val = (a0 + a1) + (a2 + a3);
    pooled[g * NF + t] = val;
    atomicAdd(&stats[t], val);
    atomicAdd(&stats[NF + t], val * val);
}

// ---------------- classifier + log_softmax (fused BN-finalize) ----------------

__global__ void k_cls(const float* __restrict__ h, const float* __restrict__ stats,
                      const float* __restrict__ gW, const float* __restrict__ bB,
                      float inv_n, const float* __restrict__ Wc,
                      const float* __restrict__ bc, float* __restrict__ out, int C_) {
    __shared__ float hr[128];
    __shared__ float lg[16];
    __shared__ float lse_s;
    int r = blockIdx.x, t = threadIdx.x;  // 64 threads
#pragma unroll
    for (int half = 0; half < 2; ++half) {
        int j = t + half * 64;
        float mean = stats[j] * inv_n;
        float var = stats[NF + j] * inv_n - mean * mean;
        float rstd = rsqrtf(var + EPS);
        float a = gW[j] * rstd;
        float c = bB[j] - mean * a;
        hr[j] = fmaf(h[r * NF + j], a, c);
    }
    __syncthreads();
    if (t < C_) {
        float s = bc[t];
        for (int k = 0; k < 128; ++k) s = fmaf(hr[k], Wc[k * C_ + t], s);
        lg[t] = s;
    }
    __syncthreads();
    if (t == 0) {
        float m = -1e30f;
        for (int c = 0; c < C_; ++c) m = fmaxf(m, lg[c]);
        float se = 0.f;
        for (int c = 0; c < C_; ++c) se += expf(lg[c] - m);
        lse_s = m + logf(se);
    }
    __syncthreads();
    if (t < C_) out[r * C_ + t] = lg[t] - lse_s;
}

// ---------------- launch ----------------

extern "C" void kernel_launch(void* const* d_in, const int* in_sizes, int n_in,
                              void* d_out, int out_size, void* d_ws, size_t ws_size,
                              hipStream_t stream) {
    const float* x          = (const float*)d_in[0];
    const int*   ei         = (const int*)d_in[1];
    const int*   batch      = (const int*)d_in[2];
    const float* bn_feat_g  = (const float*)d_in[3];
    const float* bn_feat_b  = (const float*)d_in[4];
    const float* W_feat     = (const float*)d_in[5];
    const float* bns_conv_g = (const float*)d_in[6];
    const float* bns_conv_b = (const float*)d_in[7];
    const float* W_conv     = (const float*)d_in[8];
    const float* b_conv     = (const float*)d_in[9];
    const float* bn_fc_g    = (const float*)d_in[10];
    const float* bn_fc_b    = (const float*)d_in[11];
    const float* W_lin      = (const float*)d_in[12];
    const float* b_lin      = (const float*)d_in[13];
    const float* bn_hid_g   = (const float*)d_in[14];
    const float* bn_hid_b   = (const float*)d_in[15];
    const float* W_cls      = (const float*)d_in[16];
    const float* b_cls      = (const float*)d_in[17];
    float* outp = (float*)d_out;

    const int N_ = in_sizes[2];
    const int E_ = in_sizes[1] / 2;
    const int C_ = 10;
    const int G_ = out_size / C_;

    char* wsp = (char*)d_ws;
    auto alloc = [&](size_t bytes) {
        void* p = (void*)wsp;
        wsp += (bytes + 255) & ~(size_t)255;
        return p;
    };
    // cnts and statsA adjacent -> one memset covers both
    int*      cnts   = (int*)alloc((size_t)2 * N_ * 4);     // scnt | dcnt
    float*    statsA = (float*)alloc(6 * 256 * 4);
    float*    A      = (float*)alloc((size_t)N_ * NF * 4);
    ushort_t* Bb     = (ushort_t*)alloc((size_t)(N_ + 1) * NF * 2);  // +1 zero row
    float*    dinv   = (float*)alloc((size_t)N_ * 4);
    ushort_t* colx   = (ushort_t*)alloc((size_t)N_ * KELL * 2);  // ELL ushort, stride 64
    ushort_t* Wp     = (ushort_t*)alloc((size_t)4 * NF * NF * 2);
    float*    pooled = (float*)alloc((size_t)G_ * NF * 4);
    float*    y2     = (float*)alloc((size_t)G_ * NF * 4);

    int* scnt = cnts;
    int* dcnt = cnts + N_;
    float* st_x  = statsA;
    float* st_f  = statsA + 256;
    float* st_a1 = statsA + 512;
    float* st_a2 = statsA + 768;
    float* st_pl = statsA + 1024;
    float* st_y2 = statsA + 1280;

    int nb_n = (N_ + 255) / 256;
    int nb_e = (E_ + 255) / 256;
    int nb_g = (N_ + 63) / 64;

    // one memset: cnts (aligned 2N*4) + statsA (adjacent)
    size_t cnt_rounded = (((size_t)2 * N_ * 4) + 255) & ~(size_t)255;
    hipMemsetAsync(cnts, 0, cnt_rounded + 6 * 256 * 4, stream);

    // graph prep: single atomic pass + finish (also zeros Bb sentinel row)
    k_fill_ell<<<nb_e, 256, 0, stream>>>(ei, scnt, dcnt, colx, E_);
    k_finish<<<nb_n, 256, 0, stream>>>(scnt, dcnt, dinv, colx, Bb + (size_t)N_ * NF, N_);

    // pack all 4 weight matrices once
    pack_w4<<<32, 256, 0, stream>>>(W_feat, W_conv, Wp);

    // feat: A = relu( bn(x) @ W_feat )
    bn_stats<<<512, 256, 0, stream>>>(x, st_x, N_);
    gemm_mfma<<<nb_g, 256, 0, stream>>>(x, Wp, st_x, bn_feat_g, bn_feat_b, 1.0f / N_,
                                        nullptr, nullptr, A, nullptr, N_, 1, 0);
    bn_stats<<<512, 256, 0, stream>>>(A, st_f, N_);

    // conv layers
    float* st_in[3] = {st_f, st_a1, st_a2};
    float* st_out[3] = {st_a1, st_a2, nullptr};
    for (int l = 0; l < 3; ++l) {
        gemm_mfma<<<nb_g, 256, 0, stream>>>(A, Wp + (size_t)(l + 1) * NF * NF,
                                            st_in[l], bns_conv_g + l * NF, bns_conv_b + l * NF,
                                            1.0f / N_, nullptr, dinv, nullptr, Bb, N_, 0, 1);
        k_aggregate_bf<<<(N_ + 15) / 16, 256, 0, stream>>>(Bb, dcnt, colx, dinv,
                                                           b_conv + l * NF, A, N_);
        if (st_out[l])
            bn_stats<<<512, 256, 0, stream>>>(A, st_out[l], N_);
    }

    // pool (stats fused)
    k_pool<<<G_, 128, 0, stream>>>(A, batch, pooled, st_pl, N_);

    // fc (small: vector path, fused finalize)
    gemm_bn<<<(G_ + 63) / 64, 256, 0, stream>>>(pooled, W_lin, st_pl, bn_fc_g, bn_fc_b,
                                                1.0f / G_, b_lin, y2, G_, 1);
    bn_stats<<<512, 256, 0, stream>>>(y2, st_y2, G_);

    // classifier (fused finalize)
    k_cls<<<G_, 64, 0, stream>>>(y2, st_y2, bn_hid_g, bn_hid_b, 1.0f / G_,
                                 W_cls, b_cls, outp, C_);
}